// Round 6
// baseline (5949.504 us; speedup 1.0000x reference)
//
#include <hip/hip_runtime.h>
#include <hip/hip_bf16.h>
#include <stdint.h>

#define B_  256
#define T_  512
#define H_  1024
#define BH  (B_ * H_)

typedef float  f32x4  __attribute__((ext_vector_type(4)));
typedef __bf16 bf16x8 __attribute__((ext_vector_type(8)));

__device__ inline ushort f2bf(float f) {
  union { float f; uint32_t u; } v; v.f = f;
  uint32_t u = v.u;
  return (ushort)((u + 0x7fffu + ((u >> 16) & 1u)) >> 16);   // RNE
}
__device__ inline float bf2f(ushort h) {
  union { uint32_t u; float f; } v; v.u = ((uint32_t)h) << 16;
  return v.f;
}
__device__ inline bf16x8 ld_bf8(const ushort* p) {
  union { uint4 u; bf16x8 b; } v;
  v.u = *(const uint4*)p;
  return v.b;
}
__device__ inline bf16x8 as_bf8(uint4 u) {
  union { uint4 a; bf16x8 b; } v; v.a = u; return v.b;
}
// plain cached 16B load, UNTRACKED (caller waits vmcnt). L1/L2-cacheable —
// correctness vs cross-XCD writes is provided by the acquire fence (buffer_inv)
// executed after the flag-poll and before these loads.
__device__ inline uint4 ld16_pl(const ushort* p) {
  uint4 r;
  asm volatile("global_load_dwordx4 %0, %1, off" : "=&v"(r) : "v"(p));
  return r;
}
// plain cached 2B load, untracked (xp prefetch)
__device__ inline uint32_t ld2_pf(const ushort* p) {
  uint32_t r;
  asm volatile("global_load_ushort %0, %1, off" : "=&v"(r) : "v"(p));
  return r;
}
// device-scope 2B store (to coherence point; visible to all XCDs)
__device__ inline void st_bf_coh(ushort* p, ushort v) {
  asm volatile("global_store_short %0, %1, off sc1" :: "v"(p), "v"((uint32_t)v) : "memory");
}
__device__ inline float tanh_fast(float x) {
  float xc = fminf(fmaxf(x, -15.f), 15.f);
  float e  = __expf(2.f * xc);
  return (e - 1.f) * __builtin_amdgcn_rcpf(e + 1.f);
}

// ------------------------------------------------- x_proj = xs @ Wx^T + bias
// (unchanged — passed r2-r5). Output bf16 in (T, B, H) layout.
__global__ __launch_bounds__(256) void xproj_gemm(const float* __restrict__ xs,
                                                  const float* __restrict__ W,
                                                  const float* __restrict__ bias,
                                                  ushort* __restrict__ xp) {
  __shared__ ushort As[128 * 32];
  __shared__ ushort Bs[128 * 32];
  const int bid = blockIdx.x;
  const int mt = bid >> 3, nt = bid & 7;
  const int tid = threadIdx.x;
  const int lane = tid & 63, wid = tid >> 6;
  const int wr = wid >> 1, wc = wid & 1;
  const int lr = lane & 15, lq = lane >> 4;

  const int srow = tid >> 1, scol = (tid & 1) * 16;
  const float* ag = xs + (size_t)(mt * 128 + srow) * 1024 + scol;
  const float* bg = W  + (size_t)(nt * 128 + srow) * 2048 + scol;
  ushort* as = As + srow * 32 + scol;
  ushort* bs = Bs + srow * 32 + scol;

  f32x4 acc[4][4];
#pragma unroll
  for (int m = 0; m < 4; ++m)
#pragma unroll
    for (int n = 0; n < 4; ++n) acc[m][n] = (f32x4){0.f, 0.f, 0.f, 0.f};

  for (int kc = 0; kc < 32; ++kc) {
    float4 a0 = *(const float4*)(ag + kc * 32);
    float4 a1 = *(const float4*)(ag + kc * 32 + 4);
    float4 a2 = *(const float4*)(ag + kc * 32 + 8);
    float4 a3 = *(const float4*)(ag + kc * 32 + 12);
    float4 b0 = *(const float4*)(bg + kc * 32);
    float4 b1 = *(const float4*)(bg + kc * 32 + 4);
    float4 b2 = *(const float4*)(bg + kc * 32 + 8);
    float4 b3 = *(const float4*)(bg + kc * 32 + 12);
    __syncthreads();
    {
      ushort t[16] = { f2bf(a0.x), f2bf(a0.y), f2bf(a0.z), f2bf(a0.w),
                       f2bf(a1.x), f2bf(a1.y), f2bf(a1.z), f2bf(a1.w),
                       f2bf(a2.x), f2bf(a2.y), f2bf(a2.z), f2bf(a2.w),
                       f2bf(a3.x), f2bf(a3.y), f2bf(a3.z), f2bf(a3.w) };
      *(uint4*)as       = *(const uint4*)t;
      *(uint4*)(as + 8) = *(const uint4*)(t + 8);
      ushort u[16] = { f2bf(b0.x), f2bf(b0.y), f2bf(b0.z), f2bf(b0.w),
                       f2bf(b1.x), f2bf(b1.y), f2bf(b1.z), f2bf(b1.w),
                       f2bf(b2.x), f2bf(b2.y), f2bf(b2.z), f2bf(b2.w),
                       f2bf(b3.x), f2bf(b3.y), f2bf(b3.z), f2bf(b3.w) };
      *(uint4*)bs       = *(const uint4*)u;
      *(uint4*)(bs + 8) = *(const uint4*)(u + 8);
    }
    __syncthreads();
    bf16x8 af[4], bfv[4];
#pragma unroll
    for (int m = 0; m < 4; ++m)
      af[m] = ld_bf8(As + (wr * 64 + m * 16 + lr) * 32 + lq * 8);
#pragma unroll
    for (int n = 0; n < 4; ++n)
      bfv[n] = ld_bf8(Bs + (wc * 64 + n * 16 + lr) * 32 + lq * 8);
#pragma unroll
    for (int m = 0; m < 4; ++m)
#pragma unroll
      for (int n = 0; n < 4; ++n)
        acc[m][n] = __builtin_amdgcn_mfma_f32_16x16x32_bf16(af[m], bfv[n], acc[m][n], 0, 0, 0);
  }

#pragma unroll
  for (int n = 0; n < 4; ++n) {
    int gn = nt * 128 + wc * 64 + n * 16 + lr;
    float bv = bias[gn];
#pragma unroll
    for (int m = 0; m < 4; ++m) {
      int gmb = mt * 128 + wr * 64 + m * 16 + lq * 4;
#pragma unroll
      for (int r = 0; r < 4; ++r) {
        int gm = gmb + r;
        int bi = gm >> 9, ti = gm & 511;     // m = b*512 + t
        xp[((size_t)ti * B_ + bi) * H_ + gn] = f2bf(acc[m][n][r] + bv);
      }
    }
  }
}

// ----------------------------------------------------------- persistent scan
// r5-proven structure. 128 wgs x 256 thr (4 waves). wg tile = 64 batch-rows
// x 32 H-cols; wave = 16 rows x 32 cols (2 MFMA chains), full K=1024.
// r6 deltas vs r5 (ONLY these):
//   1. A-loads are normal CACHED loads (L1/L2); correctness restored by an
//      agent-scope acquire fence (s_waitcnt + buffer_inv) after each poll.
//      -> the 32 wgs sharing a row-panel now hit L2 instead of pulling
//         128 KB/CU/step over the uncached sc1 path from L3.
//   2. XCD-aware bid swizzle: rt = (bid&7)>>1, ct = (bid>>3)+((bid&1)<<4)
//      -> each row-group's 32 wgs live on 2 XCDs; panel fetched into each
//         XCD L2 once (L3->L2 1 MB/step vs 16 MB).
__global__ __launch_bounds__(256) void rnn_scan(const float* __restrict__ W,
                                                const ushort* __restrict__ xp,
                                                ushort* __restrict__ hb,
                                                float* __restrict__ out,
                                                int* __restrict__ flags) {
  __shared__ ushort Bsm[43 * 1024];          // 86 KB declared; 64 KB used (pad
                                             // forces 1 wg/CU occupancy)
  const int bid = blockIdx.x, tid = threadIdx.x;
  const int rt = (bid & 7) >> 1;                       // XCD-pair -> row-tile
  const int ct = (bid >> 3) + ((bid & 1) << 4);        // 0..31 col-tile
  const int lane = tid & 63, wid = tid >> 6;
  const int lr = lane & 15, lq = lane >> 4;
  const int rbase = rt * 64 + wid * 16;

  // ---- one-time stage: Wh (fp32, W[:,1024:]) -> bf16 LDS, 16B-granule swizzle
  {
    const int c  = tid >> 3;                 // 0..31  (local col)
    const int qb = (tid & 7) * 16;           // 16 x 16B chunks per thread
    const float* src = W + (size_t)(ct * 32 + c) * 2048 + 1024;
    char* dst = (char*)Bsm + c * 2048;
    const int sw = (c & 7) << 4;
#pragma unroll
    for (int q = qb; q < qb + 16; ++q) {
      float4 f0 = *(const float4*)(src + q * 8);
      float4 f1 = *(const float4*)(src + q * 8 + 4);
      ushort t[8] = { f2bf(f0.x), f2bf(f0.y), f2bf(f0.z), f2bf(f0.w),
                      f2bf(f1.x), f2bf(f1.y), f2bf(f1.z), f2bf(f1.w) };
      *(uint4*)(dst + ((q * 16) ^ sw)) = *(const uint4*)t;
    }
  }
  __syncthreads();

  const int gc0 = ct * 32 + lr;              // global col of frag 0 (frag1: +16)
  const int swz = (lr & 7) << 4;
  const int kb  = lq * 16;                   // lane's k-subgroup byte offset
  const char* bp0 = (char*)Bsm + lr * 2048;
  const char* bp1 = (char*)Bsm + (16 + lr) * 2048;

  uint32_t xv[8];                            // next step's xp slice (prefetch)

  // ---- step 0: h1 = tanh(xp[0])   (h0 == 0); then prefetch xp[1]
#pragma unroll
  for (int r = 0; r < 4; ++r) {
    int gr = rbase + lq * 4 + r;
    float v0 = tanh_fast(bf2f(xp[(size_t)gr * H_ + gc0]));
    float v1 = tanh_fast(bf2f(xp[(size_t)gr * H_ + gc0 + 16]));
    st_bf_coh(hb + (size_t)gr * H_ + gc0,      f2bf(v0));
    st_bf_coh(hb + (size_t)gr * H_ + gc0 + 16, f2bf(v1));
  }
#pragma unroll
  for (int r = 0; r < 4; ++r) {
    int gr = rbase + lq * 4 + r;
    xv[r]     = ld2_pf(xp + (size_t)BH + (size_t)gr * H_ + gc0);
    xv[r + 4] = ld2_pf(xp + (size_t)BH + (size_t)gr * H_ + gc0 + 16);
  }
  asm volatile("s_waitcnt vmcnt(8)" ::: "memory");   // stores drained
  __syncthreads();
  if (tid == 0)
    __hip_atomic_store(flags + (rt * 32 + ct) * 16, 1, __ATOMIC_RELAXED, __HIP_MEMORY_SCOPE_AGENT);
  if (tid < 32) {
    while (__hip_atomic_load(flags + (rt * 32 + tid) * 16, __ATOMIC_RELAXED,
                             __HIP_MEMORY_SCOPE_AGENT) < 1) {}
  }
  __syncthreads();
  __builtin_amdgcn_fence(__ATOMIC_ACQUIRE, "agent");  // inv L1/L2 before h read

  for (int s = 1; s < T_; ++s) {
    const ushort* hprev = hb + ((s + 1) & 1) * BH;
    ushort*       hnext = hb + (s & 1) * BH;
    const ushort* arow  = hprev + (size_t)(rbase + lr) * H_ + lq * 8;

    // issue ALL 32 A-chunk loads (cached; fence already invalidated stale)
    uint4 A[32];
#pragma unroll
    for (int c = 0; c < 32; ++c) A[c] = ld16_pl(arow + c * 32);

    // first half ready; tail still in flight
    asm volatile("s_waitcnt vmcnt(16)" ::: "memory");
    __builtin_amdgcn_sched_barrier(0);

    f32x4 a0a = {0,0,0,0}, a0b = {0,0,0,0}, a1a = {0,0,0,0}, a1b = {0,0,0,0};
#pragma unroll
    for (int c = 0; c < 16; ++c) {
      const int off = ((c << 6) | kb) ^ swz;
      bf16x8 b0 = *(const bf16x8*)(bp0 + off);
      bf16x8 b1 = *(const bf16x8*)(bp1 + off);
      bf16x8 av = as_bf8(A[c]);
      if (c & 1) {
        a0b = __builtin_amdgcn_mfma_f32_16x16x32_bf16(av, b0, a0b, 0, 0, 0);
        a1b = __builtin_amdgcn_mfma_f32_16x16x32_bf16(av, b1, a1b, 0, 0, 0);
      } else {
        a0a = __builtin_amdgcn_mfma_f32_16x16x32_bf16(av, b0, a0a, 0, 0, 0);
        a1a = __builtin_amdgcn_mfma_f32_16x16x32_bf16(av, b1, a1a, 0, 0, 0);
      }
    }
    asm volatile("s_waitcnt vmcnt(0)" ::: "memory");
    __builtin_amdgcn_sched_barrier(0);
#pragma unroll
    for (int c = 16; c < 32; ++c) {
      const int off = ((c << 6) | kb) ^ swz;
      bf16x8 b0 = *(const bf16x8*)(bp0 + off);
      bf16x8 b1 = *(const bf16x8*)(bp1 + off);
      bf16x8 av = as_bf8(A[c]);
      if (c & 1) {
        a0b = __builtin_amdgcn_mfma_f32_16x16x32_bf16(av, b0, a0b, 0, 0, 0);
        a1b = __builtin_amdgcn_mfma_f32_16x16x32_bf16(av, b1, a1b, 0, 0, 0);
      } else {
        a0a = __builtin_amdgcn_mfma_f32_16x16x32_bf16(av, b0, a0a, 0, 0, 0);
        a1a = __builtin_amdgcn_mfma_f32_16x16x32_bf16(av, b1, a1a, 0, 0, 0);
      }
    }
    f32x4 acc0 = a0a + a0b, acc1 = a1a + a1b;

    if (s < T_ - 1) {
#pragma unroll
      for (int r = 0; r < 4; ++r) {
        int gr = rbase + lq * 4 + r;
        float v0 = tanh_fast(acc0[r] + bf2f((ushort)xv[r]));
        float v1 = tanh_fast(acc1[r] + bf2f((ushort)xv[r + 4]));
        st_bf_coh(hnext + (size_t)gr * H_ + gc0,      f2bf(v0));
        st_bf_coh(hnext + (size_t)gr * H_ + gc0 + 16, f2bf(v1));
      }
      // prefetch next step's xp slice (hides HBM latency under the barrier)
      const ushort* xnext = xp + (size_t)(s + 1) * BH;
#pragma unroll
      for (int r = 0; r < 4; ++r) {
        int gr = rbase + lq * 4 + r;
        xv[r]     = ld2_pf(xnext + (size_t)gr * H_ + gc0);
        xv[r + 4] = ld2_pf(xnext + (size_t)gr * H_ + gc0 + 16);
      }
      asm volatile("s_waitcnt vmcnt(8)" ::: "memory");   // 8 stores retired
      __syncthreads();
      if (tid == 0)
        __hip_atomic_store(flags + (rt * 32 + ct) * 16, s + 1, __ATOMIC_RELAXED, __HIP_MEMORY_SCOPE_AGENT);
      if (tid < 32) {
        while (__hip_atomic_load(flags + (rt * 32 + tid) * 16, __ATOMIC_RELAXED,
                                 __HIP_MEMORY_SCOPE_AGENT) < s + 1) {}
      }
      __syncthreads();
      __builtin_amdgcn_fence(__ATOMIC_ACQUIRE, "agent");  // inv before h read
    } else {
#pragma unroll
      for (int r = 0; r < 4; ++r) {
        int gr = rbase + lq * 4 + r;
        float v0 = tanh_fast(acc0[r] + bf2f((ushort)xv[r]));
        float v1 = tanh_fast(acc1[r] + bf2f((ushort)xv[r + 4]));
        out[(size_t)gr * H_ + gc0]                   = v0;
        out[(size_t)gr * H_ + gc0 + 16]              = v1;
        out[(size_t)BH + (size_t)gr * H_ + gc0]      = v0;
        out[(size_t)BH + (size_t)gr * H_ + gc0 + 16] = v1;
      }
    }
  }
}

// ---------------------------------------------------------------------- host
extern "C" void kernel_launch(void* const* d_in, const int* in_sizes, int n_in,
                              void* d_out, int out_size, void* d_ws, size_t ws_size,
                              hipStream_t stream) {
  const float* xs   = (const float*)d_in[0];
  const float* W    = (const float*)d_in[1];
  const float* bias = (const float*)d_in[2];
  float* out = (float*)d_out;
  char*  ws  = (char*)d_ws;

  const size_t XP_OFF = 0;                       // bf16 x_proj (T,B,H): 256 MiB
  const size_t HB_OFF = 268435456;               // bf16 h double-buffer: 1 MiB
  const size_t BR_OFF = HB_OFF + 1048576;        // barrier flags: 8 KiB
  const size_t NEED   = BR_OFF + 8192;
  if (ws_size < NEED) {
    hipMemsetAsync(d_out, 0, (size_t)out_size * 4, stream);
    return;
  }

  ushort* xp    = (ushort*)(ws + XP_OFF);
  ushort* hb    = (ushort*)(ws + HB_OFF);
  int*    flags = (int*)(ws + BR_OFF);

  // barrier flags must be fresh every call (ws not re-poisoned between replays)
  hipMemsetAsync(flags, 0, 128 * 16 * sizeof(int), stream);

  xproj_gemm<<<8192, 256, 0, stream>>>(xs, W, bias, xp);
  rnn_scan<<<128, 256, 0, stream>>>(W, xp, hb, out, flags);
}

// Round 7
// 3750.747 us; speedup vs baseline: 1.5862x; 1.5862x over previous
//
#include <hip/hip_runtime.h>
#include <hip/hip_bf16.h>
#include <stdint.h>

#define B_  256
#define T_  512
#define H_  1024
#define BH  (B_ * H_)

typedef float  f32x4  __attribute__((ext_vector_type(4)));
typedef __bf16 bf16x8 __attribute__((ext_vector_type(8)));

__device__ inline ushort f2bf(float f) {
  union { float f; uint32_t u; } v; v.f = f;
  uint32_t u = v.u;
  return (ushort)((u + 0x7fffu + ((u >> 16) & 1u)) >> 16);   // RNE
}
__device__ inline float bf2f(ushort h) {
  union { uint32_t u; float f; } v; v.u = ((uint32_t)h) << 16;
  return v.f;
}
__device__ inline bf16x8 ld_bf8(const ushort* p) {
  union { uint4 u; bf16x8 b; } v;
  v.u = *(const uint4*)p;
  return v.b;
}
__device__ inline bf16x8 as_bf8(uint4 u) {
  union { uint4 a; bf16x8 b; } v; v.a = u; return v.b;
}
// coherent (device-scope, L2-bypass) 16B load, UNTRACKED: caller waits vmcnt.
__device__ inline uint4 ld16_sc1(const ushort* p) {
  uint4 r;
  asm volatile("global_load_dwordx4 %0, %1, off sc1" : "=&v"(r) : "v"(p));
  return r;
}
// plain cached 2B load, untracked (xp prefetch)
__device__ inline uint32_t ld2_pf(const ushort* p) {
  uint32_t r;
  asm volatile("global_load_ushort %0, %1, off" : "=&v"(r) : "v"(p));
  return r;
}
// device-scope 2B store (to coherence point; visible to all XCDs)
__device__ inline void st_bf_coh(ushort* p, ushort v) {
  asm volatile("global_store_short %0, %1, off sc1" :: "v"(p), "v"((uint32_t)v) : "memory");
}
__device__ inline float tanh_fast(float x) {
  float xc = fminf(fmaxf(x, -15.f), 15.f);
  float e  = __expf(2.f * xc);
  return (e - 1.f) * __builtin_amdgcn_rcpf(e + 1.f);
}

// ------------------------------------------------- x_proj = xs @ Wx^T + bias
// (unchanged — passed r2-r6). Output bf16 in (T, B, H) layout.
__global__ __launch_bounds__(256) void xproj_gemm(const float* __restrict__ xs,
                                                  const float* __restrict__ W,
                                                  const float* __restrict__ bias,
                                                  ushort* __restrict__ xp) {
  __shared__ ushort As[128 * 32];
  __shared__ ushort Bs[128 * 32];
  const int bid = blockIdx.x;
  const int mt = bid >> 3, nt = bid & 7;
  const int tid = threadIdx.x;
  const int lane = tid & 63, wid = tid >> 6;
  const int wr = wid >> 1, wc = wid & 1;
  const int lr = lane & 15, lq = lane >> 4;

  const int srow = tid >> 1, scol = (tid & 1) * 16;
  const float* ag = xs + (size_t)(mt * 128 + srow) * 1024 + scol;
  const float* bg = W  + (size_t)(nt * 128 + srow) * 2048 + scol;
  ushort* as = As + srow * 32 + scol;
  ushort* bs = Bs + srow * 32 + scol;

  f32x4 acc[4][4];
#pragma unroll
  for (int m = 0; m < 4; ++m)
#pragma unroll
    for (int n = 0; n < 4; ++n) acc[m][n] = (f32x4){0.f, 0.f, 0.f, 0.f};

  for (int kc = 0; kc < 32; ++kc) {
    float4 a0 = *(const float4*)(ag + kc * 32);
    float4 a1 = *(const float4*)(ag + kc * 32 + 4);
    float4 a2 = *(const float4*)(ag + kc * 32 + 8);
    float4 a3 = *(const float4*)(ag + kc * 32 + 12);
    float4 b0 = *(const float4*)(bg + kc * 32);
    float4 b1 = *(const float4*)(bg + kc * 32 + 4);
    float4 b2 = *(const float4*)(bg + kc * 32 + 8);
    float4 b3 = *(const float4*)(bg + kc * 32 + 12);
    __syncthreads();
    {
      ushort t[16] = { f2bf(a0.x), f2bf(a0.y), f2bf(a0.z), f2bf(a0.w),
                       f2bf(a1.x), f2bf(a1.y), f2bf(a1.z), f2bf(a1.w),
                       f2bf(a2.x), f2bf(a2.y), f2bf(a2.z), f2bf(a2.w),
                       f2bf(a3.x), f2bf(a3.y), f2bf(a3.z), f2bf(a3.w) };
      *(uint4*)as       = *(const uint4*)t;
      *(uint4*)(as + 8) = *(const uint4*)(t + 8);
      ushort u[16] = { f2bf(b0.x), f2bf(b0.y), f2bf(b0.z), f2bf(b0.w),
                       f2bf(b1.x), f2bf(b1.y), f2bf(b1.z), f2bf(b1.w),
                       f2bf(b2.x), f2bf(b2.y), f2bf(b2.z), f2bf(b2.w),
                       f2bf(b3.x), f2bf(b3.y), f2bf(b3.z), f2bf(b3.w) };
      *(uint4*)bs       = *(const uint4*)u;
      *(uint4*)(bs + 8) = *(const uint4*)(u + 8);
    }
    __syncthreads();
    bf16x8 af[4], bfv[4];
#pragma unroll
    for (int m = 0; m < 4; ++m)
      af[m] = ld_bf8(As + (wr * 64 + m * 16 + lr) * 32 + lq * 8);
#pragma unroll
    for (int n = 0; n < 4; ++n)
      bfv[n] = ld_bf8(Bs + (wc * 64 + n * 16 + lr) * 32 + lq * 8);
#pragma unroll
    for (int m = 0; m < 4; ++m)
#pragma unroll
      for (int n = 0; n < 4; ++n)
        acc[m][n] = __builtin_amdgcn_mfma_f32_16x16x32_bf16(af[m], bfv[n], acc[m][n], 0, 0, 0);
  }

#pragma unroll
  for (int n = 0; n < 4; ++n) {
    int gn = nt * 128 + wc * 64 + n * 16 + lr;
    float bv = bias[gn];
#pragma unroll
    for (int m = 0; m < 4; ++m) {
      int gmb = mt * 128 + wr * 64 + m * 16 + lq * 4;
#pragma unroll
      for (int r = 0; r < 4; ++r) {
        int gm = gmb + r;
        int bi = gm >> 9, ti = gm & 511;     // m = b*512 + t
        xp[((size_t)ti * B_ + bi) * H_ + gn] = f2bf(acc[m][n][r] + bv);
      }
    }
  }
}

// ----------------------------------------------------------- persistent scan
// r5-proven sync protocol (sc1 stores + flag/poll + sc1 untracked A-loads).
// r7 geometry delta ONLY: wave tile 16x64 (4 col-frags) instead of 16x32;
// 128 wgs x 128 thr (2 waves), wg tile = 32 rows x 64 cols (8 rt x 16 ct);
// Wh slice = 64 cols = 128 KB LDS. A-issue halves: 536MB/Nc = 8 MB/step.
__global__ __launch_bounds__(128) void rnn_scan(const float* __restrict__ W,
                                                const ushort* __restrict__ xp,
                                                ushort* __restrict__ hb,
                                                float* __restrict__ out,
                                                int* __restrict__ flags) {
  __shared__ ushort Bsm[64 * 1024];          // 128 KB: Wh cols [ct*64, +64)
  const int bid = blockIdx.x, tid = threadIdx.x;
  const int rt = bid & 7, ct = bid >> 3;     // 8 row-tiles x 16 col-tiles
  const int lane = tid & 63, wid = tid >> 6; // 2 waves
  const int lr = lane & 15, lq = lane >> 4;
  const int rbase = rt * 32 + wid * 16;

  // ---- one-time stage: Wh (fp32, W[:,1024:]) -> bf16 LDS, 16B-granule swizzle
  {
    const int c    = tid >> 1;               // 0..63  (local col)
    const int half = tid & 1;                // k-half (512 floats)
    const float* src = W + (size_t)(ct * 64 + c) * 2048 + 1024 + half * 512;
    char* dst = (char*)Bsm + c * 2048;
    const int sw = (c & 7) << 4;
#pragma unroll
    for (int q = 0; q < 64; ++q) {
      float4 f0 = *(const float4*)(src + q * 8);
      float4 f1 = *(const float4*)(src + q * 8 + 4);
      ushort t[8] = { f2bf(f0.x), f2bf(f0.y), f2bf(f0.z), f2bf(f0.w),
                      f2bf(f1.x), f2bf(f1.y), f2bf(f1.z), f2bf(f1.w) };
      *(uint4*)(dst + ((half * 1024 + q * 16) ^ sw)) = *(const uint4*)t;
    }
  }
  __syncthreads();

  const int gcb = ct * 64 + lr;              // global col of frag f: gcb + f*16
  const int swz = (lr & 7) << 4;
  const int kb  = lq * 16;                   // lane's k-subgroup byte offset
  const char* bp[4] = { (char*)Bsm + lr * 2048,        (char*)Bsm + (16 + lr) * 2048,
                        (char*)Bsm + (32 + lr) * 2048, (char*)Bsm + (48 + lr) * 2048 };

  uint32_t xv[16];                           // next step's xp slice (prefetch)

  // ---- step 0: h1 = tanh(xp[0])   (h0 == 0); then prefetch xp[1]
#pragma unroll
  for (int r = 0; r < 4; ++r) {
    int gr = rbase + lq * 4 + r;
#pragma unroll
    for (int f = 0; f < 4; ++f) {
      float v = tanh_fast(bf2f(xp[(size_t)gr * H_ + gcb + f * 16]));
      st_bf_coh(hb + (size_t)gr * H_ + gcb + f * 16, f2bf(v));
    }
  }
#pragma unroll
  for (int r = 0; r < 4; ++r) {
    int gr = rbase + lq * 4 + r;
#pragma unroll
    for (int f = 0; f < 4; ++f)
      xv[r * 4 + f] = ld2_pf(xp + (size_t)BH + (size_t)gr * H_ + gcb + f * 16);
  }
  asm volatile("s_waitcnt vmcnt(16)" ::: "memory");  // 16 stores drained
  __syncthreads();
  if (tid == 0)
    __hip_atomic_store(flags + bid * 16, 1, __ATOMIC_RELAXED, __HIP_MEMORY_SCOPE_AGENT);
  if (tid < 16) {
    while (__hip_atomic_load(flags + (tid * 8 + rt) * 16, __ATOMIC_RELAXED,
                             __HIP_MEMORY_SCOPE_AGENT) < 1) {}
  }
  __syncthreads();

  for (int s = 1; s < T_; ++s) {
    const ushort* hprev = hb + ((s + 1) & 1) * BH;
    ushort*       hnext = hb + (s & 1) * BH;
    const ushort* arow  = hprev + (size_t)(rbase + lr) * H_ + lq * 8;

    // issue ALL 32 A-chunk loads (coherent, untracked)
    uint4 A[32];
#pragma unroll
    for (int c = 0; c < 32; ++c) A[c] = ld16_sc1(arow + c * 32);

    // first half ready (16 pf + 16 oldest A retired); tail in flight
    asm volatile("s_waitcnt vmcnt(16)" ::: "memory");
    __builtin_amdgcn_sched_barrier(0);

    f32x4 accA[4], accB[4];
#pragma unroll
    for (int f = 0; f < 4; ++f) { accA[f] = (f32x4){0,0,0,0}; accB[f] = (f32x4){0,0,0,0}; }

#pragma unroll
    for (int c = 0; c < 16; ++c) {
      bf16x8 av = as_bf8(A[c]);
      const int off = ((c << 6) | kb) ^ swz;
#pragma unroll
      for (int f = 0; f < 4; ++f) {
        bf16x8 bv = *(const bf16x8*)(bp[f] + off);
        if (c & 1) accB[f] = __builtin_amdgcn_mfma_f32_16x16x32_bf16(av, bv, accB[f], 0, 0, 0);
        else       accA[f] = __builtin_amdgcn_mfma_f32_16x16x32_bf16(av, bv, accA[f], 0, 0, 0);
      }
    }
    asm volatile("s_waitcnt vmcnt(0)" ::: "memory");
    __builtin_amdgcn_sched_barrier(0);
#pragma unroll
    for (int c = 16; c < 32; ++c) {
      bf16x8 av = as_bf8(A[c]);
      const int off = ((c << 6) | kb) ^ swz;
#pragma unroll
      for (int f = 0; f < 4; ++f) {
        bf16x8 bv = *(const bf16x8*)(bp[f] + off);
        if (c & 1) accB[f] = __builtin_amdgcn_mfma_f32_16x16x32_bf16(av, bv, accB[f], 0, 0, 0);
        else       accA[f] = __builtin_amdgcn_mfma_f32_16x16x32_bf16(av, bv, accA[f], 0, 0, 0);
      }
    }

    if (s < T_ - 1) {
#pragma unroll
      for (int r = 0; r < 4; ++r) {
        int gr = rbase + lq * 4 + r;
#pragma unroll
        for (int f = 0; f < 4; ++f) {
          float v = tanh_fast(accA[f][r] + accB[f][r] + bf2f((ushort)xv[r * 4 + f]));
          st_bf_coh(hnext + (size_t)gr * H_ + gcb + f * 16, f2bf(v));
        }
      }
      // prefetch next step's xp slice (flies during barrier)
      const ushort* xnext = xp + (size_t)(s + 1) * BH;
#pragma unroll
      for (int r = 0; r < 4; ++r) {
        int gr = rbase + lq * 4 + r;
#pragma unroll
        for (int f = 0; f < 4; ++f)
          xv[r * 4 + f] = ld2_pf(xnext + (size_t)gr * H_ + gcb + f * 16);
      }
      asm volatile("s_waitcnt vmcnt(16)" ::: "memory");  // 16 stores retired
      __syncthreads();
      if (tid == 0)
        __hip_atomic_store(flags + bid * 16, s + 1, __ATOMIC_RELAXED, __HIP_MEMORY_SCOPE_AGENT);
      if (tid < 16) {
        while (__hip_atomic_load(flags + (tid * 8 + rt) * 16, __ATOMIC_RELAXED,
                                 __HIP_MEMORY_SCOPE_AGENT) < s + 1) {}
      }
      __syncthreads();
    } else {
#pragma unroll
      for (int r = 0; r < 4; ++r) {
        int gr = rbase + lq * 4 + r;
#pragma unroll
        for (int f = 0; f < 4; ++f) {
          float v = tanh_fast(accA[f][r] + accB[f][r] + bf2f((ushort)xv[r * 4 + f]));
          out[(size_t)gr * H_ + gcb + f * 16]              = v;
          out[(size_t)BH + (size_t)gr * H_ + gcb + f * 16] = v;
        }
      }
    }
  }
}

// ---------------------------------------------------------------------- host
extern "C" void kernel_launch(void* const* d_in, const int* in_sizes, int n_in,
                              void* d_out, int out_size, void* d_ws, size_t ws_size,
                              hipStream_t stream) {
  const float* xs   = (const float*)d_in[0];
  const float* W    = (const float*)d_in[1];
  const float* bias = (const float*)d_in[2];
  float* out = (float*)d_out;
  char*  ws  = (char*)d_ws;

  const size_t XP_OFF = 0;                       // bf16 x_proj (T,B,H): 256 MiB
  const size_t HB_OFF = 268435456;               // bf16 h double-buffer: 1 MiB
  const size_t BR_OFF = HB_OFF + 1048576;        // barrier flags: 8 KiB
  const size_t NEED   = BR_OFF + 8192;
  if (ws_size < NEED) {
    hipMemsetAsync(d_out, 0, (size_t)out_size * 4, stream);
    return;
  }

  ushort* xp    = (ushort*)(ws + XP_OFF);
  ushort* hb    = (ushort*)(ws + HB_OFF);
  int*    flags = (int*)(ws + BR_OFF);

  // barrier flags must be fresh every call (ws not re-poisoned between replays)
  hipMemsetAsync(flags, 0, 128 * 16 * sizeof(int), stream);

  xproj_gemm<<<8192, 256, 0, stream>>>(xs, W, bias, xp);
  rnn_scan<<<128, 128, 0, stream>>>(W, xp, hb, out, flags);
}